// Round 3
// baseline (226.682 us; speedup 1.0000x reference)
//
#include <hip/hip_runtime.h>

// SelfAttention: B=4, L=4096, H=256, fp32 in/out.
// Round 12: counted-vmcnt pipeline for attn (T3/T4). r11 post-mortem: occupancy
// is register-bound at 2 waves/SIMD (124 VGPR + 64 AGPR for o[16] ~ 188 total;
// split-K cannot shrink per-wave output state), so the fix is in-wave latency,
// not TLP. Changes: (1) V staged to LDS via global_load_lds (r11 had all 4
// waves issuing IDENTICAL global V loads - 4x redundant L2 traffic ~1 GB);
// (2) raw s_barrier + s_waitcnt vmcnt(8) - never vmcnt(0) in the loop - so the
// 2-tile-deep K/V DMA prefetch stays in flight across barriers (__syncthreads
// drained it every macro in r11); (3) 32-key tiles with per-tile online
// softmax so buffer lifetime = one tile (enables the 2-deep rotation).
// Loop vmem stream is PURE DMA (8 ops/tile) so counted waits are exact.
// LDS 70656 B -> 2 blocks/CU = the register-imposed residency (no loss).
// sched_barrier(0) pins LDS reads / DMA issues against the raw barriers.
// Carried: all-fp16 attention core, DPP softmax, alpha-skip, uniform bases,
// split-K=4 grid 1024, 4-way merge, (256,2) bounds (r10 lesson: never cap).

typedef __bf16 bf16x8 __attribute__((ext_vector_type(8)));
typedef _Float16 f16x8 __attribute__((ext_vector_type(8)));
typedef _Float16 f16x4 __attribute__((ext_vector_type(4)));
typedef float floatx4 __attribute__((ext_vector_type(4)));

#define MFMA16B(a, b, c) __builtin_amdgcn_mfma_f32_16x16x32_bf16(a, b, c, 0, 0, 0)
#define MFMA16F(a, b, c) __builtin_amdgcn_mfma_f32_16x16x32_f16(a, b, c, 0, 0, 0)
#define GLOAD_LDS16(g, l)                                                  \
  __builtin_amdgcn_global_load_lds(                                        \
      (const __attribute__((address_space(1))) void *)(g),                 \
      (__attribute__((address_space(3))) void *)(l), 16, 0, 0)

#define HID 256
#define LSEQ 4096
#define NB 4
#define NTOK (NB * LSEQ)             // 16384
#define PLANE ((size_t)NTOK * HID)   // 4,194,304 elements
#define NSPLIT 4                     // split-K over key range
#define QSCALE 0.09016844005556021f  // log2(e)/16 ; softmax uses exp2

// Layouts:
//  Wht/Wlt [3][n][h] row-major hi/lo bf16 weights (transposed).
//  Qf [tok][h] row-major fp16 (pre-scaled by QSCALE).
//  Kf (32-key tiles, T = tok>>5, 512 tiles): [T][nt(2)][kc(8)][lane(64)][j(8)]
//    fp16, tile stride 8192 el (16 KB).
//    element = K[key = T*32 + nt*16 + (lane&15)][h = kc*32 + (lane>>4)*8 + j]
//  Vf (32-key tiles): [T][dt(16)][lane][j] fp16, tile stride 8192 el.
//    element = V[key = T*32 + (lane>>4)*8 + j][d = dt*16 + (lane&15)]

__device__ __forceinline__ void split_bf16(float v, __bf16 &h, __bf16 &l) {
  h = (__bf16)v;
  l = (__bf16)(v - (float)h);
}

// DPP 16-lane-row butterfly reductions (VALU, no LDS pipe).
template <int N>
__device__ __forceinline__ float dpp_ror(float v) {
  return __builtin_bit_cast(float,
      __builtin_amdgcn_update_dpp(0, __builtin_bit_cast(int, v),
                                  0x120 + N, 0xf, 0xf, true));
}
__device__ __forceinline__ float row_sum16(float v) {
  v += dpp_ror<1>(v);
  v += dpp_ror<2>(v);
  v += dpp_ror<4>(v);
  v += dpp_ror<8>(v);
  return v;
}
__device__ __forceinline__ float row_max16(float v) {
  v = fmaxf(v, dpp_ror<1>(v));
  v = fmaxf(v, dpp_ror<2>(v));
  v = fmaxf(v, dpp_ror<4>(v));
  v = fmaxf(v, dpp_ror<8>(v));
  return v;
}

// ---------------------------------------------------------------------------
// Kernel 1: transpose + hi/lo-split weights -> Wht/Wlt [3][n][h] row-major.
// ---------------------------------------------------------------------------
__global__ __launch_bounds__(256) void wsplit(const float *__restrict__ Wq,
                                              const float *__restrict__ Wk,
                                              const float *__restrict__ Wv,
                                              __bf16 *__restrict__ Wht,
                                              __bf16 *__restrict__ Wlt) {
  __shared__ float tile[32][256];
  const int wsel = blockIdx.x;
  const int hb = blockIdx.y;
  const float *W = (wsel == 0) ? Wq : (wsel == 1) ? Wk : Wv;
  __bf16 *oh = Wht + wsel * HID * HID;
  __bf16 *ol = Wlt + wsel * HID * HID;
  const int t = threadIdx.x;
  #pragma unroll
  for (int p = 0; p < 8; ++p) {
    int r = p * 4 + (t >> 6);
    int c = (t & 63) * 4;
    *(floatx4 *)&tile[r][c] = *(const floatx4 *)&W[(hb * 32 + r) * HID + c];
  }
  __syncthreads();
  #pragma unroll
  for (int q = 0; q < 4; ++q) {
    int n = q * 64 + (t >> 2);
    int hs = (t & 3) * 8;
    bf16x8 hh, ll;
    #pragma unroll
    for (int i = 0; i < 8; ++i) {
      float v = tile[hs + i][n];
      __bf16 h, l;
      split_bf16(v, h, l);
      hh[i] = h; ll[i] = l;
    }
    *(bf16x8 *)&oh[n * HID + hb * 32 + hs] = hh;
    *(bf16x8 *)&ol[n * HID + hb * 32 + hs] = ll;
  }
}

// ---------------------------------------------------------------------------
// Kernel 2: QKV projection (3-product split-bf16 GEMM, unchanged math).
// ---------------------------------------------------------------------------
__global__ __launch_bounds__(256, 2) void qkv_proj(const float *__restrict__ X,
                                                   const __bf16 *__restrict__ Wht,
                                                   const __bf16 *__restrict__ Wlt,
                                                   _Float16 *__restrict__ Qf,
                                                   _Float16 *__restrict__ Kf,
                                                   _Float16 *__restrict__ Vf) {
  __shared__ __bf16 WhS[64 * 256];
  __shared__ __bf16 WlS[64 * 256];
  _Float16 *Tf = (_Float16 *)WhS;  // 64 x 72 fp16 scratch (aliases WhS)

  const int mtile = blockIdx.x;
  const int col0 = blockIdx.y * 64;
  const int tid = threadIdx.x;
  const int w4 = tid >> 6;
  const int lane = tid & 63;
  const int quad = lane >> 4;
  const int ln = lane & 15;
  const int arow = mtile * 64 + w4 * 16 + ln;

  bf16x8 ah[8], al[8];
  #pragma unroll
  for (int kc = 0; kc < 8; ++kc) {
    const float *xp = X + (size_t)arow * HID + kc * 32 + quad * 8;
    floatx4 x0 = *(const floatx4 *)xp;
    floatx4 x1 = *(const floatx4 *)(xp + 4);
    #pragma unroll
    for (int j = 0; j < 4; ++j) {
      __bf16 h, l;
      split_bf16(x0[j], h, l); ah[kc][j] = h; al[kc][j] = l;
      split_bf16(x1[j], h, l); ah[kc][4 + j] = h; al[kc][4 + j] = l;
    }
  }

  const int srow = tid >> 2;
  const int sseg = tid & 3;

  bf16x8 pwh[8], pwl[8];
  {
    const size_t wbase = (size_t)(col0 + srow) * HID;
    #pragma unroll
    for (int j = 0; j < 8; ++j) {
      const int chunk = j * 4 + sseg;
      pwh[j] = *(const bf16x8 *)&Wht[wbase + chunk * 8];
      pwl[j] = *(const bf16x8 *)&Wlt[wbase + chunk * 8];
    }
  }

  for (int w = 0; w < 3; ++w) {
    __syncthreads();  // W region free (prev MFMA reads / scratch reads done)
    #pragma unroll
    for (int j = 0; j < 8; ++j) {
      const int chunk = j * 4 + sseg;
      const int dst = srow * 256 + ((chunk ^ (srow & 7)) << 3);
      *(bf16x8 *)&WhS[dst] = pwh[j];
      *(bf16x8 *)&WlS[dst] = pwl[j];
    }
    __syncthreads();

    if (w < 2) {
      const size_t wbase = (size_t)(w + 1) * HID * HID + (size_t)(col0 + srow) * HID;
      #pragma unroll
      for (int j = 0; j < 8; ++j) {
        const int chunk = j * 4 + sseg;
        pwh[j] = *(const bf16x8 *)&Wht[wbase + chunk * 8];
        pwl[j] = *(const bf16x8 *)&Wlt[wbase + chunk * 8];
      }
    }

    floatx4 acc[4] = {};
    #pragma unroll
    for (int kc = 0; kc < 8; ++kc) {
      #pragma unroll
      for (int nt = 0; nt < 4; ++nt) {
        const int a = (nt * 16 + ln) * 256 + (((kc * 4 + quad) ^ (ln & 7)) << 3);
        bf16x8 bh = *(const bf16x8 *)&WhS[a];
        bf16x8 bl = *(const bf16x8 *)&WlS[a];
        acc[nt] = MFMA16B(ah[kc], bh, acc[nt]);
        acc[nt] = MFMA16B(ah[kc], bl, acc[nt]);
        acc[nt] = MFMA16B(al[kc], bh, acc[nt]);
      }
    }

    // Epilogues. C/D layout: col = lane&15, row = quad*4 + reg.
    if (w == 0) {
      #pragma unroll
      for (int nt = 0; nt < 4; ++nt) {
        #pragma unroll
        for (int r = 0; r < 4; ++r) {
          const int orow = mtile * 64 + w4 * 16 + quad * 4 + r;
          const int ocol = col0 + nt * 16 + ln;
          Qf[(size_t)orow * HID + ocol] = (_Float16)(acc[nt][r] * QSCALE);
        }
      }
    } else if (w == 1) {
      __syncthreads();  // all MFMA reads of WhS done before scratch clobber
      #pragma unroll
      for (int nt = 0; nt < 4; ++nt) {
        #pragma unroll
        for (int r = 0; r < 4; ++r) {
          const int tok_l = w4 * 16 + quad * 4 + r;
          const int h_l = nt * 16 + ln;
          Tf[tok_l * 72 + h_l] = (_Float16)acc[nt][r];
        }
      }
      __syncthreads();
      #pragma unroll
      for (int i = 0; i < 2; ++i) {     // 512 chunks of 16B
        const int c = i * 256 + tid;
        const int lane_f = c & 63;
        const int ntf = (c >> 6) & 1;
        const int kcL = (c >> 7) & 1;
        const int t2 = (c >> 8) & 1;
        const int qf = lane_f >> 4;
        const int lnf = lane_f & 15;
        const int tok_l = t2 * 32 + ntf * 16 + lnf;
        f16x8 v = *(const f16x8 *)&Tf[tok_l * 72 + kcL * 32 + qf * 8];
        const int T = mtile * 2 + t2;
        const int kc = (col0 >> 5) + kcL;
        *(f16x8 *)&Kf[(size_t)T * 8192 + ((ntf * 8 + kc) * 64 + lane_f) * 8] = v;
      }
    } else {
      __syncthreads();
      #pragma unroll
      for (int nt = 0; nt < 4; ++nt) {
        #pragma unroll
        for (int r = 0; r < 4; ++r) {
          const int tok_l = w4 * 16 + quad * 4 + r;
          const int d_l = nt * 16 + ln;
          Tf[d_l * 72 + tok_l] = (_Float16)acc[nt][r];
        }
      }
      __syncthreads();
      #pragma unroll
      for (int i = 0; i < 2; ++i) {     // 512 chunks of 16B
        const int c = i * 256 + tid;
        const int lane_f = c & 63;
        const int dtL = (c >> 6) & 3;
        const int t2 = (c >> 8) & 1;
        const int qf = lane_f >> 4;
        const int lnf = lane_f & 15;
        const int d_l = dtL * 16 + lnf;
        f16x8 v = *(const f16x8 *)&Tf[d_l * 72 + t2 * 32 + qf * 8];
        const int T = mtile * 2 + t2;
        const int dt = (col0 >> 4) + dtL;
        *(f16x8 *)&Vf[(size_t)(T * 16 + dt) * 512 + lane_f * 8] = v;
      }
    }
  }
}

// ---------------------------------------------------------------------------
// Kernel 3: flash attention, counted-vmcnt pipeline. grid = 1024 (qt=bx>>2,
// ks=bx&3), 256 thr. Per 32-key tile: wait vmcnt(8) [tile's K+V DMA done,
// 2-tile-deep prefetch stays in flight] -> s_barrier -> QK (16 MFMA) ->
// online softmax-32 -> P LDS round-trip -> PV (16 MFMA) -> s_barrier ->
// issue DMA for tile+2 into this buffer. No vmcnt(0) drain in the loop.
// Loop vmem stream is pure DMA (8 ops/tile) so the counted waits are exact.
// LDS 70656 B (K dbuf 32K + V dbuf 32K + P 5K) -> 2 blocks/CU, which equals
// the register-imposed residency (124 VGPR + 64 AGPR ~ 2 waves/SIMD).
// ---------------------------------------------------------------------------
__global__ __launch_bounds__(256, 2) void attn(const _Float16 *__restrict__ Qf,
                                               const _Float16 *__restrict__ Kf,
                                               const _Float16 *__restrict__ Vf,
                                               _Float16 *__restrict__ Op,
                                               float *__restrict__ Mp,
                                               float *__restrict__ Lp) {
  __shared__ _Float16 KS[2][8192];
  __shared__ _Float16 VS[2][8192];
  __shared__ _Float16 PsS[4 * 16 * 40];  // per-wave 16 x 40 fp16

  const int bx = blockIdx.x;
  const int ks = bx & 3;
  const int qt = bx >> 2;
  const int b = qt >> 6;
  const int qtl = qt & 63;
  const int tid = threadIdx.x;
  const int w4 = tid >> 6;
  const int lane = tid & 63;
  const int quad = lane >> 4;
  const int ln = lane & 15;
  const int T0 = b * 128 + ks * 32;  // 32 key-tiles (1024 keys) per block

  const int qtok = b * LSEQ + qtl * 64 + w4 * 16 + ln;
  f16x8 q[8];
  #pragma unroll
  for (int kc = 0; kc < 8; ++kc)
    q[kc] = *(const f16x8 *)&Qf[(size_t)qtok * HID + kc * 32 + quad * 8];

  const _Float16 *kuni = Kf + (size_t)T0 * 8192;
  const _Float16 *vuni = Vf + (size_t)T0 * 8192;
  const int koff = tid * 8;
  const int voff = lane * 8;

  // Prologue: DMA tiles 0 and 1 (K then V each; 16 ops, 16 B per thread each).
  #pragma unroll
  for (int i = 0; i < 4; ++i)
    GLOAD_LDS16(kuni + i * 2048 + koff, &KS[0][i * 2048 + koff]);
  #pragma unroll
  for (int i = 0; i < 4; ++i)
    GLOAD_LDS16(vuni + i * 2048 + koff, &VS[0][i * 2048 + koff]);
  #pragma unroll
  for (int i = 0; i < 4; ++i)
    GLOAD_LDS16(kuni + 8192 + i * 2048 + koff, &KS[1][i * 2048 + koff]);
  #pragma unroll
  for (int i = 0; i < 4; ++i)
    GLOAD_LDS16(vuni + 8192 + i * 2048 + koff, &VS[1][i * 2048 + koff]);

  float m[4] = {-1e30f, -1e30f, -1e30f, -1e30f};
  float l[4] = {0.f, 0.f, 0.f, 0.f};
  floatx4 o[16] = {};
  _Float16 *ps = PsS + w4 * (16 * 40);

  // One 32-key tile. WAITN: vmcnt target (8 = keep next tile's DMA in
  // flight; 0 only for the final tile). DOISSUE: prefetch tile TT+2.
#define ATTN_TILE(TT, BUF, WAITN, DOISSUE)                                   \
  {                                                                          \
    asm volatile("s_waitcnt vmcnt(" #WAITN ")" ::: "memory");                \
    __builtin_amdgcn_s_barrier();                                            \
    __builtin_amdgcn_sched_barrier(0);                                       \
    const _Float16 *Kb = KS[BUF];                                            \
    const _Float16 *Vb = VS[BUF];                                            \
    floatx4 s0, s1;                                                          \
    {                                                                        \
      floatx4 pa0 = {}, pb0 = {}, pa1 = {}, pb1 = {};                        \
      __builtin_amdgcn_s_setprio(1);                                         \
      _Pragma("unroll")                                                      \
      for (int kc = 0; kc < 4; ++kc) {                                       \
        pa0 = MFMA16F(q[kc], *(const f16x8 *)(Kb + kc * 512 + voff), pa0);   \
        pb0 = MFMA16F(q[4 + kc], *(const f16x8 *)(Kb + (4 + kc) * 512 + voff), pb0); \
        pa1 = MFMA16F(q[kc], *(const f16x8 *)(Kb + (8 + kc) * 512 + voff), pa1);     \
        pb1 = MFMA16F(q[4 + kc], *(const f16x8 *)(Kb + (12 + kc) * 512 + voff), pb1);\
      }                                                                      \
      __builtin_amdgcn_s_setprio(0);                                         \
      s0 = pa0 + pb0;                                                        \
      s1 = pa1 + pb1;                                                        \
    }                                                                        \
    float alpha[4];                                                          \
    _Pragma("unroll")                                                        \
    for (int r = 0; r < 4; ++r) {                                            \
      const float tmax = row_max16(fmaxf(s0[r], s1[r]));                     \
      const float mn = fmaxf(m[r], tmax);                                    \
      const float al = exp2f(m[r] - mn);                                     \
      const float p0 = exp2f(s0[r] - mn);                                    \
      const float p1 = exp2f(s1[r] - mn);                                    \
      s0[r] = p0; s1[r] = p1;                                                \
      l[r] = l[r] * al + row_sum16(p0 + p1);                                 \
      m[r] = mn;                                                             \
      alpha[r] = al;                                                         \
    }                                                                        \
    _Pragma("unroll")                                                        \
    for (int r = 0; r < 4; ++r) {                                            \
      ps[(quad * 4 + r) * 40 + ln] = (_Float16)s0[r];                        \
      ps[(quad * 4 + r) * 40 + 16 + ln] = (_Float16)s1[r];                   \
    }                                                                        \
    const float amin =                                                       \
        fminf(fminf(alpha[0], alpha[1]), fminf(alpha[2], alpha[3]));         \
    if (__any(amin < 1.0f)) {                                                \
      _Pragma("unroll")                                                      \
      for (int dt = 0; dt < 16; ++dt) {                                      \
        o[dt][0] *= alpha[0]; o[dt][1] *= alpha[1];                          \
        o[dt][2] *= alpha[2]; o[dt][3] *= alpha[3];                          \
      }                                                                      \
    }                                                                        \
    const f16x8 paf = *(const f16x8 *)&ps[ln * 40 + quad * 8];               \
    __builtin_amdgcn_s_setprio(1);                                           \
    _Pragma("unroll")                                                        \
    for (int dt = 0; dt < 16; ++dt)                                          \
      o[dt] = MFMA16F(paf, *(const f16x8 *)(Vb + dt * 512 + voff), o[dt]);   \
    __builtin_amdgcn_s_setprio(0);                                           \
    __builtin_amdgcn_sched_barrier(0);                                       \
    __builtin_amdgcn_s_barrier();                                            \
    __builtin_amdgcn_sched_barrier(0);                                       \
    if (DOISSUE) {                                                           \
      const _Float16 *ksrc = kuni + (size_t)(TT + 2) * 8192 + koff;          \
      const _Float16 *vsrc = vuni + (size_t)(TT + 2) * 8192 + koff;          \
      _Pragma("unroll")                                                      \
      for (int i = 0; i < 4; ++i)                                            \
        GLOAD_LDS16(ksrc + i * 2048, &KS[BUF][i * 2048 + koff]);             \
      _Pragma("unroll")                                                      \
      for (int i = 0; i < 4; ++i)                                            \
        GLOAD_LDS16(vsrc + i * 2048, &VS[BUF][i * 2048 + koff]);             \
    }                                                                        \
  }

  for (int jm = 0; jm < 15; ++jm) {
    const int t0 = 2 * jm;
    ATTN_TILE(t0, 0, 8, 1)
    ATTN_TILE(t0 + 1, 1, 8, 1)
  }
  ATTN_TILE(30, 0, 8, 0)
  ATTN_TILE(31, 1, 0, 0)
#undef ATTN_TILE

  const int rowbase = b * LSEQ + qtl * 64 + w4 * 16 + quad * 4;
  #pragma unroll
  for (int dt = 0; dt < 16; ++dt)
    #pragma unroll
    for (int r = 0; r < 4; ++r)
      Op[(size_t)ks * PLANE + (size_t)(rowbase + r) * HID + dt * 16 + ln] =
          (_Float16)o[dt][r];
  if (ln == 0) {
    #pragma unroll
    for (int r = 0; r < 4; ++r) {
      Mp[ks * NTOK + rowbase + r] = m[r];
      Lp[ks * NTOK + rowbase + r] = l[r];
    }
  }
}

// ---------------------------------------------------------------------------
// Kernel 4: split-K merge, 4-way (fp16 partials).
// ---------------------------------------------------------------------------
__global__ __launch_bounds__(256) void merge(const _Float16 *__restrict__ Op,
                                             const float *__restrict__ Mp,
                                             const float *__restrict__ Lp,
                                             float *__restrict__ Out) {
  const int row = blockIdx.x * 4 + (threadIdx.x >> 6);
  const int c = (threadIdx.x & 63) * 4;
  float ms[NSPLIT], ls[NSPLIT];
  #pragma unroll
  for (int s = 0; s < NSPLIT; ++s) {
    ms[s] = Mp[s * NTOK + row];
    ls[s] = Lp[s * NTOK + row];
  }
  const float M = fmaxf(fmaxf(ms[0], ms[1]), fmaxf(ms[2], ms[3]));
  float e[NSPLIT], den = 0.f;
  #pragma unroll
  for (int s = 0; s < NSPLIT; ++s) {
    e[s] = exp2f(ms[s] - M);
    den += ls[s] * e[s];
  }
  const float inv = 1.0f / den;
  floatx4 out = {};
  #pragma unroll
  for (int s = 0; s < NSPLIT; ++s) {
    const f16x4 a = *(const f16x4 *)&Op[(size_t)s * PLANE + (size_t)row * HID + c];
    const float w = e[s] * inv;
    #pragma unroll
    for (int i = 0; i < 4; ++i) out[i] += w * (float)a[i];
  }
  *(floatx4 *)&Out[(size_t)row * HID + c] = out;
}

// ---------------------------------------------------------------------------
extern "C" void kernel_launch(void *const *d_in, const int *in_sizes, int n_in,
                              void *d_out, int out_size, void *d_ws, size_t ws_size,
                              hipStream_t stream) {
  const float *X = (const float *)d_in[0];
  const float *Wq = (const float *)d_in[1];
  const float *Wk = (const float *)d_in[2];
  const float *Wv = (const float *)d_in[3];
  // d_in[4] = lengths (unused by reference)

  // Workspace (2-byte elements). ~60 MB total.
  _Float16 *ws = (_Float16 *)d_ws;
  _Float16 *Qf = ws;                          // [16384][256] row-major fp16
  _Float16 *Kf = Qf + PLANE;                  // 32-key frag-linear fp16
  _Float16 *Vf = Kf + PLANE;                  // 32-key frag-linear fp16
  __bf16 *Wht = (__bf16 *)(Vf + PLANE);       // [3][256][256] bf16 hi
  __bf16 *Wlt = Wht + 3 * HID * HID;          // bf16 lo
  _Float16 *Op = (_Float16 *)(Wlt + 3 * HID * HID);  // [4][16384][256] fp16
  float *Mp = (float *)(Op + NSPLIT * PLANE); // [4][16384]
  float *Lp = Mp + NSPLIT * NTOK;             // [4][16384]

  wsplit<<<dim3(3, 8), 256, 0, stream>>>(Wq, Wk, Wv, Wht, Wlt);
  qkv_proj<<<dim3(256, 4), 256, 0, stream>>>(X, Wht, Wlt, Qf, Kf, Vf);
  attn<<<NTOK / 64 * NSPLIT, 256, 0, stream>>>(Qf, Kf, Vf, Op, Mp, Lp);
  merge<<<NTOK / 4, 256, 0, stream>>>(Op, Mp, Lp, (float *)d_out);
}

// Round 4
// 222.430 us; speedup vs baseline: 1.0191x; 1.0191x over previous
//
#include <hip/hip_runtime.h>

// SelfAttention: B=4, L=4096, H=256, fp32 in/out.
// Round 13: swapped-operand attention core (T12-style). r12 post-mortem:
// barrier count dominates (2/tile was worse than r11's 1 per 32 keys), and
// the P LDS round-trip (~250 cy serial) + DPP softmax sit inside every
// interval. Changes:
//  (1) QK computed SWAPPED: S^T = mfma(K, Q) (Q/K fragments have identical
//      per-lane layouts, so this is an argument swap). Output: q = lane&15,
//      keys in regs -> softmax is per-lane scalar (7 fmax + 2 shfl_xor).
//  (2) PV key<->k-slot bijection chosen as key(quad*8+j) = 4*quad + (j&3)
//      + 16*(j>>2), matching each lane's OWN key set -> P fragment is a pure
//      in-lane f32->f16 convert. P LDS round-trip ELIMINATED (P scratch and
//      its 524288 bank conflicts gone). Vf layout in qkv_proj changed to the
//      same bijection (two f16x4 reads from scratch instead of one f16x8).
//  (3) ONE barrier per 32-key tile: wait vmcnt(0) (queue holds only own
//      tile's 8 DMA ops, issued one full tile earlier) -> s_barrier -> issue
//      next tile -> compute. 32 barriers/block (r12 had 64).
//  (4) m/l/alpha are per-lane scalars (q=ln); O epilogue writes f16x4.
// LDS 64 KB (K dbuf 32K + V dbuf 32K), 2 blocks/CU (register-bound residency
// anyway: ~124 VGPR + 64 AGPR ~ 2 waves/SIMD). (256,2) bounds - never cap
// (r10 lesson).
// Carried: all-fp16 attention core, alpha-skip, uniform bases, split-K=4,
// grid 1024, 4-way merge, DMA K/V staging.

typedef __bf16 bf16x8 __attribute__((ext_vector_type(8)));
typedef _Float16 f16x8 __attribute__((ext_vector_type(8)));
typedef _Float16 f16x4 __attribute__((ext_vector_type(4)));
typedef float floatx4 __attribute__((ext_vector_type(4)));

#define MFMA16B(a, b, c) __builtin_amdgcn_mfma_f32_16x16x32_bf16(a, b, c, 0, 0, 0)
#define MFMA16F(a, b, c) __builtin_amdgcn_mfma_f32_16x16x32_f16(a, b, c, 0, 0, 0)
#define GLOAD_LDS16(g, l)                                                  \
  __builtin_amdgcn_global_load_lds(                                        \
      (const __attribute__((address_space(1))) void *)(g),                 \
      (__attribute__((address_space(3))) void *)(l), 16, 0, 0)

#define HID 256
#define LSEQ 4096
#define NB 4
#define NTOK (NB * LSEQ)             // 16384
#define PLANE ((size_t)NTOK * HID)   // 4,194,304 elements
#define NSPLIT 4                     // split-K over key range
#define QSCALE 0.09016844005556021f  // log2(e)/16 ; softmax uses exp2

// Layouts:
//  Wht/Wlt [3][n][h] row-major hi/lo bf16 weights (transposed).
//  Qf [tok][h] row-major fp16 (pre-scaled by QSCALE).
//  Kf (32-key tiles, T = tok>>5, 512 tiles): [T][nt(2)][kc(8)][lane(64)][j(8)]
//    fp16, tile stride 8192 el (16 KB).
//    element = K[key = T*32 + nt*16 + (lane&15)][h = kc*32 + (lane>>4)*8 + j]
//  Vf (32-key tiles): [T][dt(16)][lane][j] fp16, tile stride 8192 el.
//    element = V[key = T*32 + 4*(lane>>4) + (j&3) + 16*(j>>2)][d = dt*16 + (lane&15)]
//    (key<->k-slot bijection matches the swapped-QK per-lane key set).

__device__ __forceinline__ void split_bf16(float v, __bf16 &h, __bf16 &l) {
  h = (__bf16)v;
  l = (__bf16)(v - (float)h);
}

// ---------------------------------------------------------------------------
// Kernel 1: transpose + hi/lo-split weights -> Wht/Wlt [3][n][h] row-major.
// ---------------------------------------------------------------------------
__global__ __launch_bounds__(256) void wsplit(const float *__restrict__ Wq,
                                              const float *__restrict__ Wk,
                                              const float *__restrict__ Wv,
                                              __bf16 *__restrict__ Wht,
                                              __bf16 *__restrict__ Wlt) {
  __shared__ float tile[32][256];
  const int wsel = blockIdx.x;
  const int hb = blockIdx.y;
  const float *W = (wsel == 0) ? Wq : (wsel == 1) ? Wk : Wv;
  __bf16 *oh = Wht + wsel * HID * HID;
  __bf16 *ol = Wlt + wsel * HID * HID;
  const int t = threadIdx.x;
  #pragma unroll
  for (int p = 0; p < 8; ++p) {
    int r = p * 4 + (t >> 6);
    int c = (t & 63) * 4;
    *(floatx4 *)&tile[r][c] = *(const floatx4 *)&W[(hb * 32 + r) * HID + c];
  }
  __syncthreads();
  #pragma unroll
  for (int q = 0; q < 4; ++q) {
    int n = q * 64 + (t >> 2);
    int hs = (t & 3) * 8;
    bf16x8 hh, ll;
    #pragma unroll
    for (int i = 0; i < 8; ++i) {
      float v = tile[hs + i][n];
      __bf16 h, l;
      split_bf16(v, h, l);
      hh[i] = h; ll[i] = l;
    }
    *(bf16x8 *)&oh[n * HID + hb * 32 + hs] = hh;
    *(bf16x8 *)&ol[n * HID + hb * 32 + hs] = ll;
  }
}

// ---------------------------------------------------------------------------
// Kernel 2: QKV projection (3-product split-bf16 GEMM, unchanged math).
// V epilogue emits the NEW key<->k-slot bijection layout (see header).
// ---------------------------------------------------------------------------
__global__ __launch_bounds__(256, 2) void qkv_proj(const float *__restrict__ X,
                                                   const __bf16 *__restrict__ Wht,
                                                   const __bf16 *__restrict__ Wlt,
                                                   _Float16 *__restrict__ Qf,
                                                   _Float16 *__restrict__ Kf,
                                                   _Float16 *__restrict__ Vf) {
  __shared__ __bf16 WhS[64 * 256];
  __shared__ __bf16 WlS[64 * 256];
  _Float16 *Tf = (_Float16 *)WhS;  // 64 x 72 fp16 scratch (aliases WhS)

  const int mtile = blockIdx.x;
  const int col0 = blockIdx.y * 64;
  const int tid = threadIdx.x;
  const int w4 = tid >> 6;
  const int lane = tid & 63;
  const int quad = lane >> 4;
  const int ln = lane & 15;
  const int arow = mtile * 64 + w4 * 16 + ln;

  bf16x8 ah[8], al[8];
  #pragma unroll
  for (int kc = 0; kc < 8; ++kc) {
    const float *xp = X + (size_t)arow * HID + kc * 32 + quad * 8;
    floatx4 x0 = *(const floatx4 *)xp;
    floatx4 x1 = *(const floatx4 *)(xp + 4);
    #pragma unroll
    for (int j = 0; j < 4; ++j) {
      __bf16 h, l;
      split_bf16(x0[j], h, l); ah[kc][j] = h; al[kc][j] = l;
      split_bf16(x1[j], h, l); ah[kc][4 + j] = h; al[kc][4 + j] = l;
    }
  }

  const int srow = tid >> 2;
  const int sseg = tid & 3;

  bf16x8 pwh[8], pwl[8];
  {
    const size_t wbase = (size_t)(col0 + srow) * HID;
    #pragma unroll
    for (int j = 0; j < 8; ++j) {
      const int chunk = j * 4 + sseg;
      pwh[j] = *(const bf16x8 *)&Wht[wbase + chunk * 8];
      pwl[j] = *(const bf16x8 *)&Wlt[wbase + chunk * 8];
    }
  }

  for (int w = 0; w < 3; ++w) {
    __syncthreads();  // W region free (prev MFMA reads / scratch reads done)
    #pragma unroll
    for (int j = 0; j < 8; ++j) {
      const int chunk = j * 4 + sseg;
      const int dst = srow * 256 + ((chunk ^ (srow & 7)) << 3);
      *(bf16x8 *)&WhS[dst] = pwh[j];
      *(bf16x8 *)&WlS[dst] = pwl[j];
    }
    __syncthreads();

    if (w < 2) {
      const size_t wbase = (size_t)(w + 1) * HID * HID + (size_t)(col0 + srow) * HID;
      #pragma unroll
      for (int j = 0; j < 8; ++j) {
        const int chunk = j * 4 + sseg;
        pwh[j] = *(const bf16x8 *)&Wht[wbase + chunk * 8];
        pwl[j] = *(const bf16x8 *)&Wlt[wbase + chunk * 8];
      }
    }

    floatx4 acc[4] = {};
    #pragma unroll
    for (int kc = 0; kc < 8; ++kc) {
      #pragma unroll
      for (int nt = 0; nt < 4; ++nt) {
        const int a = (nt * 16 + ln) * 256 + (((kc * 4 + quad) ^ (ln & 7)) << 3);
        bf16x8 bh = *(const bf16x8 *)&WhS[a];
        bf16x8 bl = *(const bf16x8 *)&WlS[a];
        acc[nt] = MFMA16B(ah[kc], bh, acc[nt]);
        acc[nt] = MFMA16B(ah[kc], bl, acc[nt]);
        acc[nt] = MFMA16B(al[kc], bh, acc[nt]);
      }
    }

    // Epilogues. C/D layout: col = lane&15, row = quad*4 + reg.
    if (w == 0) {
      #pragma unroll
      for (int nt = 0; nt < 4; ++nt) {
        #pragma unroll
        for (int r = 0; r < 4; ++r) {
          const int orow = mtile * 64 + w4 * 16 + quad * 4 + r;
          const int ocol = col0 + nt * 16 + ln;
          Qf[(size_t)orow * HID + ocol] = (_Float16)(acc[nt][r] * QSCALE);
        }
      }
    } else if (w == 1) {
      __syncthreads();  // all MFMA reads of WhS done before scratch clobber
      #pragma unroll
      for (int nt = 0; nt < 4; ++nt) {
        #pragma unroll
        for (int r = 0; r < 4; ++r) {
          const int tok_l = w4 * 16 + quad * 4 + r;
          const int h_l = nt * 16 + ln;
          Tf[tok_l * 72 + h_l] = (_Float16)acc[nt][r];
        }
      }
      __syncthreads();
      #pragma unroll
      for (int i = 0; i < 2; ++i) {     // 512 chunks of 16B
        const int c = i * 256 + tid;
        const int lane_f = c & 63;
        const int ntf = (c >> 6) & 1;
        const int kcL = (c >> 7) & 1;
        const int t2 = (c >> 8) & 1;
        const int qf = lane_f >> 4;
        const int lnf = lane_f & 15;
        const int tok_l = t2 * 32 + ntf * 16 + lnf;
        f16x8 v = *(const f16x8 *)&Tf[tok_l * 72 + kcL * 32 + qf * 8];
        const int T = mtile * 2 + t2;
        const int kc = (col0 >> 5) + kcL;
        *(f16x8 *)&Kf[(size_t)T * 8192 + ((ntf * 8 + kc) * 64 + lane_f) * 8] = v;
      }
    } else {
      __syncthreads();
      #pragma unroll
      for (int nt = 0; nt < 4; ++nt) {
        #pragma unroll
        for (int r = 0; r < 4; ++r) {
          const int tok_l = w4 * 16 + quad * 4 + r;
          const int d_l = nt * 16 + ln;
          Tf[d_l * 72 + tok_l] = (_Float16)acc[nt][r];
        }
      }
      __syncthreads();
      #pragma unroll
      for (int i = 0; i < 2; ++i) {     // 512 chunks of 16B
        const int c = i * 256 + tid;
        const int lane_f = c & 63;
        const int dtL = (c >> 6) & 3;
        const int t2 = (c >> 8) & 1;
        const int qf = lane_f >> 4;
        const int lnf = lane_f & 15;
        const int d_l = dtL * 16 + lnf;
        // New bijection: v[j] = V_local[key = t2*32 + 4*qf + (j&3) + 16*(j>>2)][d_l]
        f16x4 lo = *(const f16x4 *)&Tf[d_l * 72 + t2 * 32 + 4 * qf];
        f16x4 hi = *(const f16x4 *)&Tf[d_l * 72 + t2 * 32 + 16 + 4 * qf];
        f16x8 v;
        v[0] = lo[0]; v[1] = lo[1]; v[2] = lo[2]; v[3] = lo[3];
        v[4] = hi[0]; v[5] = hi[1]; v[6] = hi[2]; v[7] = hi[3];
        const int T = mtile * 2 + t2;
        const int dt = (col0 >> 4) + dtL;
        *(f16x8 *)&Vf[(size_t)(T * 16 + dt) * 512 + lane_f * 8] = v;
      }
    }
  }
}

// ---------------------------------------------------------------------------
// Kernel 3: flash attention, swapped-operand core. grid = 1024 (qt=bx>>2,
// ks=bx&3), 256 thr, LDS 64 KB (K/V double-buffered 32-key tiles).
// Per tile: wait vmcnt(0) [only own tile's 8 DMA ops in queue, issued one
// tile earlier] -> s_barrier -> issue tile t+1 -> QK^T swapped (16 MFMA) ->
// per-lane softmax (7 fmax + 2 shfl_xor; 8 exp2) -> in-lane P cvt ->
// PV (16 MFMA). No P LDS round-trip. One barrier per tile.
// ---------------------------------------------------------------------------
__global__ __launch_bounds__(256, 2) void attn(const _Float16 *__restrict__ Qf,
                                               const _Float16 *__restrict__ Kf,
                                               const _Float16 *__restrict__ Vf,
                                               _Float16 *__restrict__ Op,
                                               float *__restrict__ Mp,
                                               float *__restrict__ Lp) {
  __shared__ _Float16 KS[2][8192];
  __shared__ _Float16 VS[2][8192];

  const int bx = blockIdx.x;
  const int ks = bx & 3;
  const int qt = bx >> 2;
  const int b = qt >> 6;
  const int qtl = qt & 63;
  const int tid = threadIdx.x;
  const int w4 = tid >> 6;
  const int lane = tid & 63;
  const int quad = lane >> 4;
  const int ln = lane & 15;
  const int T0 = b * 128 + ks * 32;  // 32 key-tiles (1024 keys) per block

  // This lane's q token (q = lane&15 in the swapped layout).
  const int qtok = b * LSEQ + qtl * 64 + w4 * 16 + ln;
  f16x8 q[8];
  #pragma unroll
  for (int kc = 0; kc < 8; ++kc)
    q[kc] = *(const f16x8 *)&Qf[(size_t)qtok * HID + kc * 32 + quad * 8];

  const _Float16 *kuni = Kf + (size_t)T0 * 8192;
  const _Float16 *vuni = Vf + (size_t)T0 * 8192;
  const int koff = tid * 8;
  const int voff = lane * 8;

  // Prologue: DMA tile 0 -> buffers 0.
  #pragma unroll
  for (int i = 0; i < 4; ++i)
    GLOAD_LDS16(kuni + i * 2048 + koff, &KS[0][i * 2048 + koff]);
  #pragma unroll
  for (int i = 0; i < 4; ++i)
    GLOAD_LDS16(vuni + i * 2048 + koff, &VS[0][i * 2048 + koff]);

  float m = -1e30f;
  float l = 0.f;
  floatx4 o[16] = {};

  for (int t = 0; t < 32; ++t) {
    const int buf = t & 1;
    // Own tile-t DMA done (issued one full tile ago); queue holds nothing
    // else, so this drain is the minimal correct wait.
    asm volatile("s_waitcnt vmcnt(0)" ::: "memory");
    __builtin_amdgcn_s_barrier();  // all waves' quarters in LDS; prev bufs free
    __builtin_amdgcn_sched_barrier(0);
    if (t < 31) {
      const _Float16 *ksrc = kuni + (size_t)(t + 1) * 8192 + koff;
      const _Float16 *vsrc = vuni + (size_t)(t + 1) * 8192 + koff;
      #pragma unroll
      for (int i = 0; i < 4; ++i)
        GLOAD_LDS16(ksrc + i * 2048, &KS[buf ^ 1][i * 2048 + koff]);
      #pragma unroll
      for (int i = 0; i < 4; ++i)
        GLOAD_LDS16(vsrc + i * 2048, &VS[buf ^ 1][i * 2048 + koff]);
    }
    const _Float16 *Kb = KS[buf];
    const _Float16 *Vb = VS[buf];

    // ---------- QK^T swapped: S^T[key][q] = mfma(K, Q) ----------
    floatx4 s0, s1;
    {
      floatx4 pa0 = {}, pb0 = {}, pa1 = {}, pb1 = {};
      __builtin_amdgcn_s_setprio(1);
      #pragma unroll
      for (int kc = 0; kc < 4; ++kc) {
        pa0 = MFMA16F(*(const f16x8 *)(Kb + kc * 512 + voff), q[kc], pa0);
        pb0 = MFMA16F(*(const f16x8 *)(Kb + (4 + kc) * 512 + voff), q[4 + kc], pb0);
        pa1 = MFMA16F(*(const f16x8 *)(Kb + (8 + kc) * 512 + voff), q[kc], pa1);
        pb1 = MFMA16F(*(const f16x8 *)(Kb + (12 + kc) * 512 + voff), q[4 + kc], pb1);
      }
      __builtin_amdgcn_s_setprio(0);
      s0 = pa0 + pb0;  // keys quad*4+r      (nt=0)
      s1 = pa1 + pb1;  // keys 16+quad*4+r   (nt=1)
    }

    // ---------- per-lane softmax over 32 keys (q = ln) ----------
    float tmax = fmaxf(fmaxf(fmaxf(s0[0], s0[1]), fmaxf(s0[2], s0[3])),
                       fmaxf(fmaxf(s1[0], s1[1]), fmaxf(s1[2], s1[3])));
    tmax = fmaxf(tmax, __shfl_xor(tmax, 16));
    tmax = fmaxf(tmax, __shfl_xor(tmax, 32));
    const float mn = fmaxf(m, tmax);
    const float al = exp2f(m - mn);
    #pragma unroll
    for (int i = 0; i < 4; ++i) {
      s0[i] = exp2f(s0[i] - mn);
      s1[i] = exp2f(s1[i] - mn);
    }
    float rs = ((s0[0] + s0[1]) + (s0[2] + s0[3])) +
               ((s1[0] + s1[1]) + (s1[2] + s1[3]));
    rs += __shfl_xor(rs, 16);
    rs += __shfl_xor(rs, 32);
    l = l * al + rs;
    m = mn;

    // ---------- P fragment: pure in-lane cvt (keys 4q+(j&3)+16*(j>>2)) -----
    f16x8 pf;
    pf[0] = (_Float16)s0[0]; pf[1] = (_Float16)s0[1];
    pf[2] = (_Float16)s0[2]; pf[3] = (_Float16)s0[3];
    pf[4] = (_Float16)s1[0]; pf[5] = (_Float16)s1[1];
    pf[6] = (_Float16)s1[2]; pf[7] = (_Float16)s1[3];

    // ---------- O rescale (alpha-skip) ----------
    if (__any(al < 1.0f)) {
      #pragma unroll
      for (int dt = 0; dt < 16; ++dt) {
        o[dt][0] *= al; o[dt][1] *= al; o[dt][2] *= al; o[dt][3] *= al;
      }
    }

    // ---------- O^T += V^T P : o[dt][r] = O[q=ln][d=dt*16+quad*4+r] --------
    __builtin_amdgcn_s_setprio(1);
    #pragma unroll
    for (int dt = 0; dt < 16; ++dt)
      o[dt] = MFMA16F(*(const f16x8 *)(Vb + dt * 512 + voff), pf, o[dt]);
    __builtin_amdgcn_s_setprio(0);
    __builtin_amdgcn_sched_barrier(0);
  }

  // Epilogue: per lane owns q = qtok; d = dt*16 + quad*4 + r -> f16x4 stores.
  #pragma unroll
  for (int dt = 0; dt < 16; ++dt) {
    f16x4 v4;
    v4[0] = (_Float16)o[dt][0]; v4[1] = (_Float16)o[dt][1];
    v4[2] = (_Float16)o[dt][2]; v4[3] = (_Float16)o[dt][3];
    *(f16x4 *)&Op[(size_t)ks * PLANE + (size_t)qtok * HID + dt * 16 + quad * 4] = v4;
  }
  if (quad == 0) {
    Mp[ks * NTOK + qtok] = m;
    Lp[ks * NTOK + qtok] = l;
  }
}

// ---------------------------------------------------------------------------
// Kernel 4: split-K merge, 4-way (fp16 partials).
// ---------------------------------------------------------------------------
__global__ __launch_bounds__(256) void merge(const _Float16 *__restrict__ Op,
                                             const float *__restrict__ Mp,
                                             const float *__restrict__ Lp,
                                             float *__restrict__ Out) {
  const int row = blockIdx.x * 4 + (threadIdx.x >> 6);
  const int c = (threadIdx.x & 63) * 4;
  float ms[NSPLIT], ls[NSPLIT];
  #pragma unroll
  for (int s = 0; s < NSPLIT; ++s) {
    ms[s] = Mp[s * NTOK + row];
    ls[s] = Lp[s * NTOK + row];
  }
  const float M = fmaxf(fmaxf(ms[0], ms[1]), fmaxf(ms[2], ms[3]));
  float e[NSPLIT], den = 0.f;
  #pragma unroll
  for (int s = 0; s < NSPLIT; ++s) {
    e[s] = exp2f(ms[s] - M);
    den += ls[s] * e[s];
  }
  const float inv = 1.0f / den;
  floatx4 out = {};
  #pragma unroll
  for (int s = 0; s < NSPLIT; ++s) {
    const f16x4 a = *(const f16x4 *)&Op[(size_t)s * PLANE + (size_t)row * HID + c];
    const float w = e[s] * inv;
    #pragma unroll
    for (int i = 0; i < 4; ++i) out[i] += w * (float)a[i];
  }
  *(floatx4 *)&Out[(size_t)row * HID + c] = out;
}

// ---------------------------------------------------------------------------
extern "C" void kernel_launch(void *const *d_in, const int *in_sizes, int n_in,
                              void *d_out, int out_size, void *d_ws, size_t ws_size,
                              hipStream_t stream) {
  const float *X = (const float *)d_in[0];
  const float *Wq = (const float *)d_in[1];
  const float *Wk = (const float *)d_in[2];
  const float *Wv = (const float *)d_in[3];
  // d_in[4] = lengths (unused by reference)

  // Workspace (2-byte elements). ~60 MB total.
  _Float16 *ws = (_Float16 *)d_ws;
  _Float16 *Qf = ws;                          // [16384][256] row-major fp16
  _Float16 *Kf = Qf + PLANE;                  // 32-key frag-linear fp16
  _Float16 *Vf = Kf + PLANE;                  // 32-key frag-linear fp16
  __bf16 *Wht = (__bf16 *)(Vf + PLANE);       // [3][256][256] bf16 hi
  __bf16 *Wlt = Wht + 3 * HID * HID;          // bf16 lo
  _Float16 *Op = (_Float16 *)(Wlt + 3 * HID * HID);  // [4][16384][256] fp16
  float *Mp = (float *)(Op + NSPLIT * PLANE); // [4][16384]
  float *Lp = Mp + NSPLIT * NTOK;             // [4][16384]

  wsplit<<<dim3(3, 8), 256, 0, stream>>>(Wq, Wk, Wv, Wht, Wlt);
  qkv_proj<<<dim3(256, 4), 256, 0, stream>>>(X, Wht, Wlt, Qf, Kf, Vf);
  attn<<<NTOK / 64 * NSPLIT, 256, 0, stream>>>(Qf, Kf, Vf, Op, Mp, Lp);
  merge<<<NTOK / 4, 256, 0, stream>>>(Op, Mp, Lp, (float *)d_out);
}

// Round 5
// 209.899 us; speedup vs baseline: 1.0800x; 1.0597x over previous
//
#include <hip/hip_runtime.h>

// SelfAttention: B=4, L=4096, H=256, fp32 in/out.
// Round 14: 2 q-sets per wave (q-block 128). r13 post-mortem: bank conflicts
// ->0 as predicted but dur only -9%: the real limiter is LDS READ bandwidth.
// Per tile all 4 waves read the same 32 KB of K+V: 160 KB LDS traffic per
// block-tile x2 blocks/CU ~ 2500 cyc at 128 B/cyc, matching the measured
// ~4600 cyc/tile far above the ~320 cyc MFMA floor. Fix: each wave carries
// TWO q-fragment sets (32 q-tokens), so every K/V ds_read_b128 feeds 2 MFMAs
// -> LDS reads per unit work halve AND grid halves (512 blocks = one
// 2-blocks/CU dispatch round instead of two). Registers: o0/o1 (128) +
// q0/q1 (64) + temps ~ 240 < the 256 cap of (256,2) - no spill expected
// (r10 lesson: the cap must exceed need).
// Carried from r13: swapped-operand QK (S^T = mfma(K,Q)), per-lane scalar
// softmax (q = lane&15), in-lane P cvt via the Vf key<->k-slot bijection
// (key = 4*quad + (j&3) + 16*(j>>2)), one barrier + counted DMA per tile,
// K/V DMA-staged LDS dbuf, alpha-skip, split-K=4, 4-way merge.

typedef __bf16 bf16x8 __attribute__((ext_vector_type(8)));
typedef _Float16 f16x8 __attribute__((ext_vector_type(8)));
typedef _Float16 f16x4 __attribute__((ext_vector_type(4)));
typedef float floatx4 __attribute__((ext_vector_type(4)));

#define MFMA16B(a, b, c) __builtin_amdgcn_mfma_f32_16x16x32_bf16(a, b, c, 0, 0, 0)
#define MFMA16F(a, b, c) __builtin_amdgcn_mfma_f32_16x16x32_f16(a, b, c, 0, 0, 0)
#define GLOAD_LDS16(g, l)                                                  \
  __builtin_amdgcn_global_load_lds(                                        \
      (const __attribute__((address_space(1))) void *)(g),                 \
      (__attribute__((address_space(3))) void *)(l), 16, 0, 0)

#define HID 256
#define LSEQ 4096
#define NB 4
#define NTOK (NB * LSEQ)             // 16384
#define PLANE ((size_t)NTOK * HID)   // 4,194,304 elements
#define NSPLIT 4                     // split-K over key range
#define QSCALE 0.09016844005556021f  // log2(e)/16 ; softmax uses exp2

// Layouts:
//  Wht/Wlt [3][n][h] row-major hi/lo bf16 weights (transposed).
//  Qf [tok][h] row-major fp16 (pre-scaled by QSCALE).
//  Kf (32-key tiles, T = tok>>5, 512 tiles): [T][nt(2)][kc(8)][lane(64)][j(8)]
//    fp16, tile stride 8192 el (16 KB).
//    element = K[key = T*32 + nt*16 + (lane&15)][h = kc*32 + (lane>>4)*8 + j]
//  Vf (32-key tiles): [T][dt(16)][lane][j] fp16, tile stride 8192 el.
//    element = V[key = T*32 + 4*(lane>>4) + (j&3) + 16*(j>>2)][d = dt*16 + (lane&15)]
//    (key<->k-slot bijection matches the swapped-QK per-lane key set).

__device__ __forceinline__ void split_bf16(float v, __bf16 &h, __bf16 &l) {
  h = (__bf16)v;
  l = (__bf16)(v - (float)h);
}

// ---------------------------------------------------------------------------
// Kernel 1: transpose + hi/lo-split weights -> Wht/Wlt [3][n][h] row-major.
// ---------------------------------------------------------------------------
__global__ __launch_bounds__(256) void wsplit(const float *__restrict__ Wq,
                                              const float *__restrict__ Wk,
                                              const float *__restrict__ Wv,
                                              __bf16 *__restrict__ Wht,
                                              __bf16 *__restrict__ Wlt) {
  __shared__ float tile[32][256];
  const int wsel = blockIdx.x;
  const int hb = blockIdx.y;
  const float *W = (wsel == 0) ? Wq : (wsel == 1) ? Wk : Wv;
  __bf16 *oh = Wht + wsel * HID * HID;
  __bf16 *ol = Wlt + wsel * HID * HID;
  const int t = threadIdx.x;
  #pragma unroll
  for (int p = 0; p < 8; ++p) {
    int r = p * 4 + (t >> 6);
    int c = (t & 63) * 4;
    *(floatx4 *)&tile[r][c] = *(const floatx4 *)&W[(hb * 32 + r) * HID + c];
  }
  __syncthreads();
  #pragma unroll
  for (int q = 0; q < 4; ++q) {
    int n = q * 64 + (t >> 2);
    int hs = (t & 3) * 8;
    bf16x8 hh, ll;
    #pragma unroll
    for (int i = 0; i < 8; ++i) {
      float v = tile[hs + i][n];
      __bf16 h, l;
      split_bf16(v, h, l);
      hh[i] = h; ll[i] = l;
    }
    *(bf16x8 *)&oh[n * HID + hb * 32 + hs] = hh;
    *(bf16x8 *)&ol[n * HID + hb * 32 + hs] = ll;
  }
}

// ---------------------------------------------------------------------------
// Kernel 2: QKV projection (3-product split-bf16 GEMM, unchanged math).
// V epilogue emits the key<->k-slot bijection layout (see header).
// ---------------------------------------------------------------------------
__global__ __launch_bounds__(256, 2) void qkv_proj(const float *__restrict__ X,
                                                   const __bf16 *__restrict__ Wht,
                                                   const __bf16 *__restrict__ Wlt,
                                                   _Float16 *__restrict__ Qf,
                                                   _Float16 *__restrict__ Kf,
                                                   _Float16 *__restrict__ Vf) {
  __shared__ __bf16 WhS[64 * 256];
  __shared__ __bf16 WlS[64 * 256];
  _Float16 *Tf = (_Float16 *)WhS;  // 64 x 72 fp16 scratch (aliases WhS)

  const int mtile = blockIdx.x;
  const int col0 = blockIdx.y * 64;
  const int tid = threadIdx.x;
  const int w4 = tid >> 6;
  const int lane = tid & 63;
  const int quad = lane >> 4;
  const int ln = lane & 15;
  const int arow = mtile * 64 + w4 * 16 + ln;

  bf16x8 ah[8], al[8];
  #pragma unroll
  for (int kc = 0; kc < 8; ++kc) {
    const float *xp = X + (size_t)arow * HID + kc * 32 + quad * 8;
    floatx4 x0 = *(const floatx4 *)xp;
    floatx4 x1 = *(const floatx4 *)(xp + 4);
    #pragma unroll
    for (int j = 0; j < 4; ++j) {
      __bf16 h, l;
      split_bf16(x0[j], h, l); ah[kc][j] = h; al[kc][j] = l;
      split_bf16(x1[j], h, l); ah[kc][4 + j] = h; al[kc][4 + j] = l;
    }
  }

  const int srow = tid >> 2;
  const int sseg = tid & 3;

  bf16x8 pwh[8], pwl[8];
  {
    const size_t wbase = (size_t)(col0 + srow) * HID;
    #pragma unroll
    for (int j = 0; j < 8; ++j) {
      const int chunk = j * 4 + sseg;
      pwh[j] = *(const bf16x8 *)&Wht[wbase + chunk * 8];
      pwl[j] = *(const bf16x8 *)&Wlt[wbase + chunk * 8];
    }
  }

  for (int w = 0; w < 3; ++w) {
    __syncthreads();  // W region free (prev MFMA reads / scratch reads done)
    #pragma unroll
    for (int j = 0; j < 8; ++j) {
      const int chunk = j * 4 + sseg;
      const int dst = srow * 256 + ((chunk ^ (srow & 7)) << 3);
      *(bf16x8 *)&WhS[dst] = pwh[j];
      *(bf16x8 *)&WlS[dst] = pwl[j];
    }
    __syncthreads();

    if (w < 2) {
      const size_t wbase = (size_t)(w + 1) * HID * HID + (size_t)(col0 + srow) * HID;
      #pragma unroll
      for (int j = 0; j < 8; ++j) {
        const int chunk = j * 4 + sseg;
        pwh[j] = *(const bf16x8 *)&Wht[wbase + chunk * 8];
        pwl[j] = *(const bf16x8 *)&Wlt[wbase + chunk * 8];
      }
    }

    floatx4 acc[4] = {};
    #pragma unroll
    for (int kc = 0; kc < 8; ++kc) {
      #pragma unroll
      for (int nt = 0; nt < 4; ++nt) {
        const int a = (nt * 16 + ln) * 256 + (((kc * 4 + quad) ^ (ln & 7)) << 3);
        bf16x8 bh = *(const bf16x8 *)&WhS[a];
        bf16x8 bl = *(const bf16x8 *)&WlS[a];
        acc[nt] = MFMA16B(ah[kc], bh, acc[nt]);
        acc[nt] = MFMA16B(ah[kc], bl, acc[nt]);
        acc[nt] = MFMA16B(al[kc], bh, acc[nt]);
      }
    }

    // Epilogues. C/D layout: col = lane&15, row = quad*4 + reg.
    if (w == 0) {
      #pragma unroll
      for (int nt = 0; nt < 4; ++nt) {
        #pragma unroll
        for (int r = 0; r < 4; ++r) {
          const int orow = mtile * 64 + w4 * 16 + quad * 4 + r;
          const int ocol = col0 + nt * 16 + ln;
          Qf[(size_t)orow * HID + ocol] = (_Float16)(acc[nt][r] * QSCALE);
        }
      }
    } else if (w == 1) {
      __syncthreads();  // all MFMA reads of WhS done before scratch clobber
      #pragma unroll
      for (int nt = 0; nt < 4; ++nt) {
        #pragma unroll
        for (int r = 0; r < 4; ++r) {
          const int tok_l = w4 * 16 + quad * 4 + r;
          const int h_l = nt * 16 + ln;
          Tf[tok_l * 72 + h_l] = (_Float16)acc[nt][r];
        }
      }
      __syncthreads();
      #pragma unroll
      for (int i = 0; i < 2; ++i) {     // 512 chunks of 16B
        const int c = i * 256 + tid;
        const int lane_f = c & 63;
        const int ntf = (c >> 6) & 1;
        const int kcL = (c >> 7) & 1;
        const int t2 = (c >> 8) & 1;
        const int qf = lane_f >> 4;
        const int lnf = lane_f & 15;
        const int tok_l = t2 * 32 + ntf * 16 + lnf;
        f16x8 v = *(const f16x8 *)&Tf[tok_l * 72 + kcL * 32 + qf * 8];
        const int T = mtile * 2 + t2;
        const int kc = (col0 >> 5) + kcL;
        *(f16x8 *)&Kf[(size_t)T * 8192 + ((ntf * 8 + kc) * 64 + lane_f) * 8] = v;
      }
    } else {
      __syncthreads();
      #pragma unroll
      for (int nt = 0; nt < 4; ++nt) {
        #pragma unroll
        for (int r = 0; r < 4; ++r) {
          const int tok_l = w4 * 16 + quad * 4 + r;
          const int d_l = nt * 16 + ln;
          Tf[d_l * 72 + tok_l] = (_Float16)acc[nt][r];
        }
      }
      __syncthreads();
      #pragma unroll
      for (int i = 0; i < 2; ++i) {     // 512 chunks of 16B
        const int c = i * 256 + tid;
        const int lane_f = c & 63;
        const int dtL = (c >> 6) & 3;
        const int t2 = (c >> 8) & 1;
        const int qf = lane_f >> 4;
        const int lnf = lane_f & 15;
        const int d_l = dtL * 16 + lnf;
        // Bijection: v[j] = V_local[key = t2*32 + 4*qf + (j&3) + 16*(j>>2)][d_l]
        f16x4 lo = *(const f16x4 *)&Tf[d_l * 72 + t2 * 32 + 4 * qf];
        f16x4 hi = *(const f16x4 *)&Tf[d_l * 72 + t2 * 32 + 16 + 4 * qf];
        f16x8 v;
        v[0] = lo[0]; v[1] = lo[1]; v[2] = lo[2]; v[3] = lo[3];
        v[4] = hi[0]; v[5] = hi[1]; v[6] = hi[2]; v[7] = hi[3];
        const int T = mtile * 2 + t2;
        const int dt = (col0 >> 4) + dtL;
        *(f16x8 *)&Vf[(size_t)(T * 16 + dt) * 512 + lane_f * 8] = v;
      }
    }
  }
}

// ---------------------------------------------------------------------------
// Kernel 3: flash attention, swapped-operand core, 2 q-sets/wave.
// grid = 512 (qt=bx>>2 over 128-token q-blocks, ks=bx&3), 256 thr,
// LDS 64 KB (K/V dbuf), one 2-blocks/CU dispatch round.
// Per 32-key tile: wait vmcnt(0) -> s_barrier -> issue tile t+1 DMA ->
// QK^T swapped (16 K-frag reads, 32 MFMA) -> 2x per-lane softmax ->
// 2x in-lane P cvt -> PV (16 V-frag reads, 32 MFMA). Every LDS fragment
// read feeds TWO MFMAs (the round-14 lever).
// ---------------------------------------------------------------------------
__global__ __launch_bounds__(256, 2) void attn(const _Float16 *__restrict__ Qf,
                                               const _Float16 *__restrict__ Kf,
                                               const _Float16 *__restrict__ Vf,
                                               _Float16 *__restrict__ Op,
                                               float *__restrict__ Mp,
                                               float *__restrict__ Lp) {
  __shared__ _Float16 KS[2][8192];
  __shared__ _Float16 VS[2][8192];

  const int bx = blockIdx.x;
  const int ks = bx & 3;
  const int qt = bx >> 2;            // 0..127: 128-token q-block
  const int b = qt >> 5;             // 32 q-blocks per batch
  const int qtl = qt & 31;
  const int tid = threadIdx.x;
  const int w4 = tid >> 6;
  const int lane = tid & 63;
  const int quad = lane >> 4;
  const int ln = lane & 15;
  const int T0 = b * 128 + ks * 32;  // 32 key-tiles (1024 keys) per block

  // This lane's two q tokens (q = lane&15 in the swapped layout).
  const int qtok0 = b * LSEQ + qtl * 128 + w4 * 16 + ln;
  const int qtok1 = qtok0 + 64;
  f16x8 q0[8], q1[8];
  #pragma unroll
  for (int kc = 0; kc < 8; ++kc) {
    q0[kc] = *(const f16x8 *)&Qf[(size_t)qtok0 * HID + kc * 32 + quad * 8];
    q1[kc] = *(const f16x8 *)&Qf[(size_t)qtok1 * HID + kc * 32 + quad * 8];
  }

  const _Float16 *kuni = Kf + (size_t)T0 * 8192;
  const _Float16 *vuni = Vf + (size_t)T0 * 8192;
  const int koff = tid * 8;
  const int voff = lane * 8;

  // Prologue: DMA tile 0 -> buffers 0.
  #pragma unroll
  for (int i = 0; i < 4; ++i)
    GLOAD_LDS16(kuni + i * 2048 + koff, &KS[0][i * 2048 + koff]);
  #pragma unroll
  for (int i = 0; i < 4; ++i)
    GLOAD_LDS16(vuni + i * 2048 + koff, &VS[0][i * 2048 + koff]);

  float m0 = -1e30f, m1 = -1e30f;
  float l0 = 0.f, l1 = 0.f;
  floatx4 o0[16] = {}, o1[16] = {};

  for (int t = 0; t < 32; ++t) {
    const int buf = t & 1;
    // Own tile-t DMA done (issued one full tile ago); queue empty otherwise.
    asm volatile("s_waitcnt vmcnt(0)" ::: "memory");
    __builtin_amdgcn_s_barrier();  // all waves' quarters in LDS; prev bufs free
    __builtin_amdgcn_sched_barrier(0);
    if (t < 31) {
      const _Float16 *ksrc = kuni + (size_t)(t + 1) * 8192 + koff;
      const _Float16 *vsrc = vuni + (size_t)(t + 1) * 8192 + koff;
      #pragma unroll
      for (int i = 0; i < 4; ++i)
        GLOAD_LDS16(ksrc + i * 2048, &KS[buf ^ 1][i * 2048 + koff]);
      #pragma unroll
      for (int i = 0; i < 4; ++i)
        GLOAD_LDS16(vsrc + i * 2048, &VS[buf ^ 1][i * 2048 + koff]);
    }
    const _Float16 *Kb = KS[buf];
    const _Float16 *Vb = VS[buf];

    // ---------- QK^T swapped: S^T = mfma(K, Q); each K-frag feeds 2 MFMAs --
    floatx4 s00, s01, s10, s11;  // s{qset}{nt}
    {
      floatx4 a00 = {}, b00 = {}, a01 = {}, b01 = {};
      floatx4 a10 = {}, b10 = {}, a11 = {}, b11 = {};
      __builtin_amdgcn_s_setprio(1);
      #pragma unroll
      for (int kc = 0; kc < 4; ++kc) {
        const f16x8 k0 = *(const f16x8 *)(Kb + kc * 512 + voff);
        const f16x8 k1 = *(const f16x8 *)(Kb + (4 + kc) * 512 + voff);
        const f16x8 k2 = *(const f16x8 *)(Kb + (8 + kc) * 512 + voff);
        const f16x8 k3 = *(const f16x8 *)(Kb + (12 + kc) * 512 + voff);
        a00 = MFMA16F(k0, q0[kc], a00);
        a10 = MFMA16F(k0, q1[kc], a10);
        b00 = MFMA16F(k1, q0[4 + kc], b00);
        b10 = MFMA16F(k1, q1[4 + kc], b10);
        a01 = MFMA16F(k2, q0[kc], a01);
        a11 = MFMA16F(k2, q1[kc], a11);
        b01 = MFMA16F(k3, q0[4 + kc], b01);
        b11 = MFMA16F(k3, q1[4 + kc], b11);
      }
      __builtin_amdgcn_s_setprio(0);
      s00 = a00 + b00; s01 = a01 + b01;
      s10 = a10 + b10; s11 = a11 + b11;
    }

    // ---------- per-lane softmax over 32 keys, q-set 0 (q = ln) ----------
    float al0, al1;
    {
      float tmax = fmaxf(fmaxf(fmaxf(s00[0], s00[1]), fmaxf(s00[2], s00[3])),
                         fmaxf(fmaxf(s01[0], s01[1]), fmaxf(s01[2], s01[3])));
      tmax = fmaxf(tmax, __shfl_xor(tmax, 16));
      tmax = fmaxf(tmax, __shfl_xor(tmax, 32));
      const float mn = fmaxf(m0, tmax);
      al0 = exp2f(m0 - mn);
      #pragma unroll
      for (int i = 0; i < 4; ++i) {
        s00[i] = exp2f(s00[i] - mn);
        s01[i] = exp2f(s01[i] - mn);
      }
      float rs = ((s00[0] + s00[1]) + (s00[2] + s00[3])) +
                 ((s01[0] + s01[1]) + (s01[2] + s01[3]));
      rs += __shfl_xor(rs, 16);
      rs += __shfl_xor(rs, 32);
      l0 = l0 * al0 + rs;
      m0 = mn;
    }
    // ---------- q-set 1 ----------
    {
      float tmax = fmaxf(fmaxf(fmaxf(s10[0], s10[1]), fmaxf(s10[2], s10[3])),
                         fmaxf(fmaxf(s11[0], s11[1]), fmaxf(s11[2], s11[3])));
      tmax = fmaxf(tmax, __shfl_xor(tmax, 16));
      tmax = fmaxf(tmax, __shfl_xor(tmax, 32));
      const float mn = fmaxf(m1, tmax);
      al1 = exp2f(m1 - mn);
      #pragma unroll
      for (int i = 0; i < 4; ++i) {
        s10[i] = exp2f(s10[i] - mn);
        s11[i] = exp2f(s11[i] - mn);
      }
      float rs = ((s10[0] + s10[1]) + (s10[2] + s10[3])) +
                 ((s11[0] + s11[1]) + (s11[2] + s11[3]));
      rs += __shfl_xor(rs, 16);
      rs += __shfl_xor(rs, 32);
      l1 = l1 * al1 + rs;
      m1 = mn;
    }

    // ---------- P fragments: pure in-lane cvt ----------
    f16x8 pf0, pf1;
    pf0[0] = (_Float16)s00[0]; pf0[1] = (_Float16)s00[1];
    pf0[2] = (_Float16)s00[2]; pf0[3] = (_Float16)s00[3];
    pf0[4] = (_Float16)s01[0]; pf0[5] = (_Float16)s01[1];
    pf0[6] = (_Float16)s01[2]; pf0[7] = (_Float16)s01[3];
    pf1[0] = (_Float16)s10[0]; pf1[1] = (_Float16)s10[1];
    pf1[2] = (_Float16)s10[2]; pf1[3] = (_Float16)s10[3];
    pf1[4] = (_Float16)s11[0]; pf1[5] = (_Float16)s11[1];
    pf1[6] = (_Float16)s11[2]; pf1[7] = (_Float16)s11[3];

    // ---------- O rescale (alpha-skip, per q-set) ----------
    if (__any(al0 < 1.0f)) {
      #pragma unroll
      for (int dt = 0; dt < 16; ++dt) {
        o0[dt][0] *= al0; o0[dt][1] *= al0; o0[dt][2] *= al0; o0[dt][3] *= al0;
      }
    }
    if (__any(al1 < 1.0f)) {
      #pragma unroll
      for (int dt = 0; dt < 16; ++dt) {
        o1[dt][0] *= al1; o1[dt][1] *= al1; o1[dt][2] *= al1; o1[dt][3] *= al1;
      }
    }

    // ---------- O^T += V^T P ; each V-frag feeds 2 MFMAs ----------
    __builtin_amdgcn_s_setprio(1);
    #pragma unroll
    for (int dt = 0; dt < 16; ++dt) {
      const f16x8 vf = *(const f16x8 *)(Vb + dt * 512 + voff);
      o0[dt] = MFMA16F(vf, pf0, o0[dt]);
      o1[dt] = MFMA16F(vf, pf1, o1[dt]);
    }
    __builtin_amdgcn_s_setprio(0);
    __builtin_amdgcn_sched_barrier(0);
  }

  // Epilogue: lane owns q = qtok0/qtok1; d = dt*16 + quad*4 + r.
  #pragma unroll
  for (int dt = 0; dt < 16; ++dt) {
    f16x4 v4;
    v4[0] = (_Float16)o0[dt][0]; v4[1] = (_Float16)o0[dt][1];
    v4[2] = (_Float16)o0[dt][2]; v4[3] = (_Float16)o0[dt][3];
    *(f16x4 *)&Op[(size_t)ks * PLANE + (size_t)qtok0 * HID + dt * 16 + quad * 4] = v4;
    f16x4 w4v;
    w4v[0] = (_Float16)o1[dt][0]; w4v[1] = (_Float16)o1[dt][1];
    w4v[2] = (_Float16)o1[dt][2]; w4v[3] = (_Float16)o1[dt][3];
    *(f16x4 *)&Op[(size_t)ks * PLANE + (size_t)qtok1 * HID + dt * 16 + quad * 4] = w4v;
  }
  if (quad == 0) {
    Mp[ks * NTOK + qtok0] = m0;
    Lp[ks * NTOK + qtok0] = l0;
    Mp[ks * NTOK + qtok1] = m1;
    Lp[ks * NTOK + qtok1] = l1;
  }
}

// ---------------------------------------------------------------------------
// Kernel 4: split-K merge, 4-way (fp16 partials).
// ---------------------------------------------------------------------------
__global__ __launch_bounds__(256) void merge(const _Float16 *__restrict__ Op,
                                             const float *__restrict__ Mp,
                                             const float *__restrict__ Lp,
                                             float *__restrict__ Out) {
  const int row = blockIdx.x * 4 + (threadIdx.x >> 6);
  const int c = (threadIdx.x & 63) * 4;
  float ms[NSPLIT], ls[NSPLIT];
  #pragma unroll
  for (int s = 0; s < NSPLIT; ++s) {
    ms[s] = Mp[s * NTOK + row];
    ls[s] = Lp[s * NTOK + row];
  }
  const float M = fmaxf(fmaxf(ms[0], ms[1]), fmaxf(ms[2], ms[3]));
  float e[NSPLIT], den = 0.f;
  #pragma unroll
  for (int s = 0; s < NSPLIT; ++s) {
    e[s] = exp2f(ms[s] - M);
    den += ls[s] * e[s];
  }
  const float inv = 1.0f / den;
  floatx4 out = {};
  #pragma unroll
  for (int s = 0; s < NSPLIT; ++s) {
    const f16x4 a = *(const f16x4 *)&Op[(size_t)s * PLANE + (size_t)row * HID + c];
    const float w = e[s] * inv;
    #pragma unroll
    for (int i = 0; i < 4; ++i) out[i] += w * (float)a[i];
  }
  *(floatx4 *)&Out[(size_t)row * HID + c] = out;
}

// ---------------------------------------------------------------------------
extern "C" void kernel_launch(void *const *d_in, const int *in_sizes, int n_in,
                              void *d_out, int out_size, void *d_ws, size_t ws_size,
                              hipStream_t stream) {
  const float *X = (const float *)d_in[0];
  const float *Wq = (const float *)d_in[1];
  const float *Wk = (const float *)d_in[2];
  const float *Wv = (const float *)d_in[3];
  // d_in[4] = lengths (unused by reference)

  // Workspace (2-byte elements). ~60 MB total.
  _Float16 *ws = (_Float16 *)d_ws;
  _Float16 *Qf = ws;                          // [16384][256] row-major fp16
  _Float16 *Kf = Qf + PLANE;                  // 32-key frag-linear fp16
  _Float16 *Vf = Kf + PLANE;                  // 32-key frag-linear fp16
  __bf16 *Wht = (__bf16 *)(Vf + PLANE);       // [3][256][256] bf16 hi
  __bf16 *Wlt = Wht + 3 * HID * HID;          // bf16 lo
  _Float16 *Op = (_Float16 *)(Wlt + 3 * HID * HID);  // [4][16384][256] fp16
  float *Mp = (float *)(Op + NSPLIT * PLANE); // [4][16384]
  float *Lp = Mp + NSPLIT * NTOK;             // [4][16384]

  wsplit<<<dim3(3, 8), 256, 0, stream>>>(Wq, Wk, Wv, Wht, Wlt);
  qkv_proj<<<dim3(256, 4), 256, 0, stream>>>(X, Wht, Wlt, Qf, Kf, Vf);
  attn<<<NTOK / 128 * NSPLIT, 256, 0, stream>>>(Qf, Kf, Vf, Op, Mp, Lp);
  merge<<<NTOK / 4, 256, 0, stream>>>(Op, Mp, Lp, (float *)d_out);
}